// Round 13
// baseline (4626.082 us; speedup 1.0000x reference)
//
#include <hip/hip_runtime.h>
#include <hip/hip_cooperative_groups.h>
#include <math.h>

namespace cg = cooperative_groups;

#define N_NODES 50000
#define N_EDGES 800000
#define DIN 128
#define DH 256
#define DOUT 64
#define NLAYERS 4
#define MEGA_BLOCKS 1024  // 4 blocks/CU x 256 CUs (launch_bounds 256,4)

typedef unsigned short u16;
typedef __attribute__((ext_vector_type(8))) _Float16 half8;
typedef __attribute__((ext_vector_type(4))) float f32x4;
typedef __attribute__((ext_vector_type(4), aligned(8))) int int4a;

__device__ inline u16 f2h(float f) {
  _Float16 h = (_Float16)f;
  return *(u16*)&h;
}
__device__ inline float h2f(u16 u) {
  _Float16 h = *(_Float16*)&u;
  return (float)h;
}
// stored index j -> true feature index (perm: true c -> (c%16)*4 + c/16 per 64-seg)
__device__ inline int invp(int j) {
  int s = j >> 6, t = j & 63;
  return s * 64 + (t & 3) * 16 + (t >> 2);
}

#define GLD16(gp, lp)                                                        \
  __builtin_amdgcn_global_load_lds(                                          \
      (const __attribute__((address_space(1))) void*)(const void*)(gp),      \
      (__attribute__((address_space(3))) void*)(void*)(lp), 16, 0, 0)

#define X_Q (N_NODES * DIN / 4)        // 1,600,000 float4 groups
#define W_EMB_SZ (DIN * DH)            // 32768
#define W_CONV_SZ (DH * DH)            // 65536
#define W_OUT_SZ (3 * DH * DOUT)       // 49152
#define W_TOT (W_EMB_SZ + 4 * W_CONV_SZ + W_OUT_SZ)
#define B_TOT (DH + 4 * DH)
#define CVT_TOT (X_Q + W_TOT + B_TOT + N_NODES)

struct MegaArgs {
  const float* x;
  const int* esrc;
  const int* edst;
  const float* W_emb;
  const float* b_emb;
  const float* W_conv;
  const float* b_conv;
  const float* W_out;
  const float* b_out;
  float* out;
  u16* tmph;
  u16* h_hi;
  u16* h_lo;
  u16* x_f16;
  float* dinv;
  int* cnt;
  int* rowptr;
  int* cursor;
  int* bsum;
  int2* csr;
  u16* Bt_emb;
  u16* Bt_conv;
  u16* Bt_out;
  float* bEmbP;
  float* bConvP;
};

// ---- convert (x, weights, biases) + cnt zeroing; range CVT_TOT ----
__device__ inline void cvt_one(int i, const MegaArgs& a) {
  if (i < X_Q) {
    float4 v = ((const float4*)a.x)[i];
    ushort4 o;
    o.x = f2h(v.x); o.y = f2h(v.y); o.z = f2h(v.z); o.w = f2h(v.w);
    ((ushort4*)a.x_f16)[i] = o;
    return;
  }
  int t = i - X_Q;
  if (t < W_EMB_SZ) {
    int n = t >> 7, k = t & (DIN - 1);
    a.Bt_emb[t] = f2h(a.W_emb[k * DH + n]);
  } else if (t < W_EMB_SZ + 4 * W_CONV_SZ) {
    int j = t - W_EMB_SZ;
    int l = j >> 16, jj = j & (W_CONV_SZ - 1);
    int n = jj >> 8, k2 = jj & (DH - 1);
    a.Bt_conv[j] = f2h(a.W_conv[l * W_CONV_SZ + invp(k2) * DH + n]);
  } else if (t < W_TOT) {
    int j = t - W_EMB_SZ - 4 * W_CONV_SZ;
    int n = j / (3 * DH), kp = j % (3 * DH);
    int s0 = kp >> 8, k2 = kp & (DH - 1);
    float wv = a.W_out[invp(k2) * DOUT + n];
    u16 hiv = f2h(wv);
    u16 v = hiv;
    if (s0 == 1) v = f2h(wv - h2f(hiv));
    a.Bt_out[j] = v;
  } else {
    int t2 = t - W_TOT;
    if (t2 < B_TOT) {
      if (t2 < DH) a.bEmbP[t2] = a.b_emb[invp(t2)];
      else {
        int j = t2 - DH, l = j >> 8, jj = j & (DH - 1);
        a.bConvP[j] = a.b_conv[l * DH + invp(jj)];
      }
    } else {
      int t3 = t2 - B_TOT;
      if (t3 < N_NODES) a.cnt[t3] = 0;
    }
  }
}

// ---- f16 MFMA GEMM tile (4 waves, BM=128, BK=64; proven body) ----
// EPI 0: Cf fp32 + bias, TRUE col order. EPI 1: Cb f16 + biasp, PERM cols.
template <int BN, int NSPLIT, int EPI>
__device__ inline void gemm_tile(int m0, int n0,
    const u16* __restrict__ Ahi, const u16* __restrict__ Alo,
    const u16* __restrict__ Bt, const float* __restrict__ bias,
    float* __restrict__ Cf, u16* __restrict__ Cb, int M, int K, int N,
    u16* As) {
  constexpr int BK = 64;
  constexpr int WN = BN / 2;
  constexpr int NT = WN / 16;
  const int tid = threadIdx.x;
  const int w = tid >> 6, lane = tid & 63;
  const int q = lane >> 4, r = lane & 15;
  const int wmg = (w >> 1) * 4;
  const int wn = (w & 1) * WN;
  const int Kp = NSPLIT * K;
  const int srow = lane & 15;
  const int sk = (lane >> 4) * 8;

  f32x4 acc[4][NT];
#pragma unroll
  for (int t = 0; t < 4; t++)
#pragma unroll
    for (int u = 0; u < NT; u++) acc[t][u] = (f32x4){0.f, 0.f, 0.f, 0.f};

  for (int k0 = 0; k0 < Kp; k0 += BK) {
    const u16* Aptr;
    int ka;
    if (NSPLIT == 1) {
      Aptr = Ahi; ka = k0;
    } else {
      Aptr = (k0 < 2 * K) ? Ahi : Alo;
      ka = (k0 < K) ? k0 : ((k0 < 2 * K) ? (k0 - K) : (k0 - 2 * K));
    }
#pragma unroll
    for (int ii = 0; ii < 4; ii++) {
      int g = w * 2 + (ii & 1), kb = ii >> 1;
      int grow = m0 + g * 16 + srow;
      if (grow > M - 1) grow = M - 1;
      const u16* gp = Aptr + (size_t)grow * K + ka + kb * 32 + sk;
      GLD16(gp, &As[(kb * 8 + g) * 512] + (size_t)lane * 8);
    }
    __syncthreads();
#pragma unroll
    for (int kb = 0; kb < 2; kb++) {
      half8 af[4], bfr[NT];
#pragma unroll
      for (int u = 0; u < NT; u++)
        bfr[u] = *(const half8*)(Bt + (size_t)(n0 + wn + u * 16 + r) * Kp +
                                 k0 + kb * 32 + q * 8);
#pragma unroll
      for (int t = 0; t < 4; t++)
        af[t] = *(const half8*)&As[((kb * 8 + wmg + t) * 64 + lane) * 8];
#pragma unroll
      for (int t = 0; t < 4; t++)
#pragma unroll
        for (int u = 0; u < NT; u++)
          acc[t][u] = __builtin_amdgcn_mfma_f32_16x16x32_f16(af[t], bfr[u], acc[t][u], 0, 0, 0);
    }
    __syncthreads();
  }

  const int rowb = m0 + (w >> 1) * 64;
  if constexpr (EPI == 1) {
    static_assert(NT == 4, "perm epilogue requires BN=128");
    int c = n0 + wn + r * 4;
    float4 bp = bias ? *(const float4*)(bias + c) : make_float4(0.f, 0.f, 0.f, 0.f);
#pragma unroll
    for (int t = 0; t < 4; t++) {
#pragma unroll
      for (int rg = 0; rg < 4; rg++) {
        int row = rowb + t * 16 + q * 4 + rg;
        if (row < M) {
          ushort4 o;
          o.x = f2h(acc[t][0][rg] + bp.x);
          o.y = f2h(acc[t][1][rg] + bp.y);
          o.z = f2h(acc[t][2][rg] + bp.z);
          o.w = f2h(acc[t][3][rg] + bp.w);
          *(ushort4*)(Cb + (size_t)row * N + c) = o;
        }
      }
    }
  } else {
    float bv[NT];
#pragma unroll
    for (int u = 0; u < NT; u++) bv[u] = bias ? bias[n0 + wn + u * 16 + r] : 0.f;
#pragma unroll
    for (int t = 0; t < 4; t++) {
#pragma unroll
      for (int rg = 0; rg < 4; rg++) {
        int row = rowb + t * 16 + q * 4 + rg;
        if (row < M) {
#pragma unroll
          for (int u = 0; u < NT; u++) {
            int col = n0 + wn + u * 16 + r;
            Cf[(size_t)row * N + col] = acc[t][u][rg] + bv[u];
          }
        }
      }
    }
  }
}

// ---- aggregation, one node per wave (round-1 body, proven 60.5 us) ----
__device__ inline void agg_node(int i, const u16* __restrict__ tmph,
    const int* __restrict__ rowptr, const int2* __restrict__ csr,
    const float* __restrict__ dinv, const float* __restrict__ bias,
    u16* __restrict__ hi, u16* __restrict__ lo, int lane) {
  float w0 = dinv[i];
  w0 *= w0;
  const ushort4* T = (const ushort4*)tmph;
  float4 bv = ((const float4*)bias)[lane];
  int s = rowptr[i], e = rowptr[i + 1];
  ushort4 t0 = T[(size_t)i * 64 + lane];
  float ax = bv.x + w0 * h2f(t0.x);
  float ay = bv.y + w0 * h2f(t0.y);
  float az = bv.z + w0 * h2f(t0.z);
  float aw = bv.w + w0 * h2f(t0.w);
  int j = s;
  for (; j + 16 <= e; j += 16) {
    int4a q[8];
#pragma unroll
    for (int u = 0; u < 8; u++) q[u] = *(const int4a*)(csr + j + 2 * u);
    ushort4 v[16];
#pragma unroll
    for (int u = 0; u < 8; u++) {
      v[2 * u] = T[(size_t)q[u].x * 64 + lane];
      v[2 * u + 1] = T[(size_t)q[u].z * 64 + lane];
    }
#pragma unroll
    for (int u = 0; u < 8; u++) {
      float f0 = __int_as_float(q[u].y);
      ax += f0 * h2f(v[2 * u].x);
      ay += f0 * h2f(v[2 * u].y);
      az += f0 * h2f(v[2 * u].z);
      aw += f0 * h2f(v[2 * u].w);
      float f1 = __int_as_float(q[u].w);
      ax += f1 * h2f(v[2 * u + 1].x);
      ay += f1 * h2f(v[2 * u + 1].y);
      az += f1 * h2f(v[2 * u + 1].z);
      aw += f1 * h2f(v[2 * u + 1].w);
    }
  }
  if (j < e) {
    int2 c[16];
    float f[16];
    ushort4 v[16];
#pragma unroll
    for (int u = 0; u < 16; u++) {
      int idx = j + u;
      int cl = idx < e ? idx : e - 1;
      c[u] = csr[cl];
      f[u] = idx < e ? __int_as_float(c[u].y) : 0.f;
    }
#pragma unroll
    for (int u = 0; u < 16; u++) v[u] = T[(size_t)c[u].x * 64 + lane];
#pragma unroll
    for (int u = 0; u < 16; u++) {
      ax += f[u] * h2f(v[u].x);
      ay += f[u] * h2f(v[u].y);
      az += f[u] * h2f(v[u].z);
      aw += f[u] * h2f(v[u].w);
    }
  }
  float ox = tanhf(ax), oy = tanhf(ay), oz = tanhf(az), ow = tanhf(aw);
  size_t base = (size_t)i * DH + lane * 4;
  ushort4 hv;
  hv.x = f2h(ox); hv.y = f2h(oy); hv.z = f2h(oz); hv.w = f2h(ow);
  *(ushort4*)(hi + base) = hv;
  if (lo) {
    ushort4 lv;
    lv.x = f2h(ox - h2f(hv.x));
    lv.y = f2h(oy - h2f(hv.y));
    lv.z = f2h(oz - h2f(hv.z));
    lv.w = f2h(ow - h2f(hv.w));
    *(ushort4*)(lo + base) = lv;
  }
}

// ---- mega kernel: all phases, explicit agent fences around every grid.sync ----
__device__ inline void gsync(cg::grid_group& g) {
  __threadfence();   // release: write back dirty L2 (cross-XCD visibility)
  g.sync();
  __threadfence();   // acquire: invalidate L1/L2 before reading others' writes
}

__global__ __launch_bounds__(256, 4) void k_mega(MegaArgs a) {
  cg::grid_group grid = cg::this_grid();
  __shared__ __align__(16) u16 As[2 * 8 * 512];  // 16 KB; aliased as int[] for scans
  int* sm = (int*)As;
  const int tid = threadIdx.x;
  const int gid = blockIdx.x * 256 + tid;
  const int gsz = gridDim.x * 256;
  const int nb = (N_NODES + 255) / 256;
  const int mb = (N_NODES + 127) / 128;

  // P0: convert + zero cnt
  for (int i = gid; i < CVT_TOT; i += gsz) cvt_one(i, a);
  gsync(grid);
  // P1: degree histogram
  for (int i = gid; i < N_EDGES; i += gsz) atomicAdd(&a.cnt[a.edst[i]], 1);
  gsync(grid);
  // P2: per-256-chunk inclusive scan + dinv
  for (int c = blockIdx.x; c < nb; c += gridDim.x) {
    int i = c * 256 + tid;
    int v = (i < N_NODES) ? a.cnt[i] : 0;
    if (i < N_NODES) a.dinv[i] = rsqrtf((float)v + 1.0f);
    __syncthreads();
    sm[tid] = v;
    __syncthreads();
    for (int off = 1; off < 256; off <<= 1) {
      int t = (tid >= off) ? sm[tid - off] : 0;
      __syncthreads();
      sm[tid] += t;
      __syncthreads();
    }
    if (i < N_NODES) a.rowptr[i + 1] = sm[tid];
    if (tid == 255) a.bsum[c] = sm[255];
  }
  gsync(grid);
  // P3: block-sum exclusive scan (nb=196 <= 256)
  if (blockIdx.x == 0) {
    int v = (tid < nb) ? a.bsum[tid] : 0;
    sm[tid] = v;
    __syncthreads();
    for (int off = 1; off < 256; off <<= 1) {
      int t = (tid >= off) ? sm[tid - off] : 0;
      __syncthreads();
      sm[tid] += t;
      __syncthreads();
    }
    if (tid < nb) a.bsum[tid] = sm[tid] - v;
  }
  gsync(grid);
  // P4: add block offsets + cursor init
  for (int c = blockIdx.x; c < nb; c += gridDim.x) {
    int i = c * 256 + tid;
    if (i < N_NODES) {
      int v = a.rowptr[i + 1] + a.bsum[c];
      a.rowptr[i + 1] = v;
      if (i + 1 < N_NODES) a.cursor[i + 1] = v;
    }
  }
  if (gid == 0) { a.rowptr[0] = 0; a.cursor[0] = 0; }
  gsync(grid);
  // P5: fill csr
  for (int i = gid; i < N_EDGES; i += gsz) {
    int d = a.edst[i], s = a.esrc[i];
    int pos = atomicAdd(&a.cursor[d], 1);
    a.csr[pos] = make_int2(s, __float_as_int(a.dinv[s] * a.dinv[d]));
  }
  gsync(grid);
  // P6: emb GEMM  h0 = x @ W_emb + b_emb -> h_hi (perm cols)
  for (int t = blockIdx.x; t < mb * 2; t += gridDim.x)
    gemm_tile<128, 1, 1>((t >> 1) * 128, (t & 1) * 128, a.x_f16, nullptr,
                         a.Bt_emb, a.bEmbP, nullptr, a.h_hi, N_NODES, DIN, DH, As);
  gsync(grid);
  // layers
  for (int l = 0; l < NLAYERS; l++) {
    const u16* Bt = a.Bt_conv + (size_t)l * W_CONV_SZ;
    for (int t = blockIdx.x; t < mb * 2; t += gridDim.x)
      gemm_tile<128, 1, 1>((t >> 1) * 128, (t & 1) * 128, a.h_hi, nullptr,
                           Bt, nullptr, nullptr, a.tmph, N_NODES, DH, DH, As);
    gsync(grid);
    {
      const int lane = tid & 63;
      u16* lo = (l == 3) ? a.h_lo : nullptr;
      const float* bi = a.bConvP + (size_t)l * DH;
      for (int iw = blockIdx.x * 4 + (tid >> 6); iw < N_NODES; iw += gridDim.x * 4) {
        int i = __builtin_amdgcn_readfirstlane(iw);
        agg_node(i, a.tmph, a.rowptr, a.csr, a.dinv, bi, a.h_hi, lo, lane);
      }
    }
    gsync(grid);
  }
  // out GEMM (split-3, fp32 out, TRUE col order)
  for (int t = blockIdx.x; t < mb; t += gridDim.x)
    gemm_tile<64, 3, 0>(t * 128, 0, a.h_hi, a.h_lo, a.Bt_out, a.b_out,
                        a.out, nullptr, N_NODES, DH, DOUT, As);
}

// ---------------- fallback kernels (round-11 proven path) ----------------

__global__ void k_convert_fb(MegaArgs a) {
  int i = blockIdx.x * 256 + threadIdx.x;
  if (i < CVT_TOT) cvt_one(i, a);
}

__global__ void k_hist(const int* __restrict__ edst, int* __restrict__ cnt) {
  int i = blockIdx.x * 256 + threadIdx.x;
  if (i < N_EDGES) atomicAdd(&cnt[edst[i]], 1);
}

__global__ void k_scan1(const int* __restrict__ cnt, int* __restrict__ rowptr,
                        int* __restrict__ bsum, float* __restrict__ dinv, int n) {
  __shared__ int sm[256];
  int i = blockIdx.x * 256 + threadIdx.x;
  int v = (i < n) ? cnt[i] : 0;
  if (i < n) dinv[i] = rsqrtf((float)v + 1.0f);
  sm[threadIdx.x] = v;
  __syncthreads();
  for (int off = 1; off < 256; off <<= 1) {
    int t = (threadIdx.x >= off) ? sm[threadIdx.x - off] : 0;
    __syncthreads();
    sm[threadIdx.x] += t;
    __syncthreads();
  }
  if (i < n) rowptr[i + 1] = sm[threadIdx.x];
  if (threadIdx.x == 255) bsum[blockIdx.x] = sm[255];
}

__global__ void k_scan2(int* bsum, int nb) {
  __shared__ int sm[256];
  int v = (threadIdx.x < nb) ? bsum[threadIdx.x] : 0;
  sm[threadIdx.x] = v;
  __syncthreads();
  for (int off = 1; off < 256; off <<= 1) {
    int t = (threadIdx.x >= off) ? sm[threadIdx.x - off] : 0;
    __syncthreads();
    sm[threadIdx.x] += t;
    __syncthreads();
  }
  if (threadIdx.x < nb) bsum[threadIdx.x] = sm[threadIdx.x] - v;
}

__global__ void k_scan3(int* __restrict__ rowptr, const int* __restrict__ bsum,
                        int* __restrict__ cursor, int n) {
  int i = blockIdx.x * 256 + threadIdx.x;
  if (i < n) {
    int v = rowptr[i + 1] + bsum[blockIdx.x];
    rowptr[i + 1] = v;
    if (i + 1 < n) cursor[i + 1] = v;
  }
  if (blockIdx.x == 0 && threadIdx.x == 0) {
    rowptr[0] = 0;
    cursor[0] = 0;
  }
}

__global__ void k_fill(const int* __restrict__ src, const int* __restrict__ dst,
                       const float* __restrict__ dinv,
                       int* __restrict__ cursor, int2* __restrict__ csr, int e) {
  int i = blockIdx.x * blockDim.x + threadIdx.x;
  if (i < e) {
    int d = dst[i], s = src[i];
    int pos = atomicAdd(&cursor[d], 1);
    csr[pos] = make_int2(s, __float_as_int(dinv[s] * dinv[d]));
  }
}

template <int BN, int NSPLIT, int EPI>
__global__ __launch_bounds__(256) void k_gemm(
    const u16* __restrict__ Ahi, const u16* __restrict__ Alo,
    const u16* __restrict__ Bt, const float* __restrict__ bias,
    float* __restrict__ Cf, u16* __restrict__ Cb, int M, int K, int N) {
  __shared__ __align__(16) u16 As[2 * 8 * 512];
  gemm_tile<BN, NSPLIT, EPI>(blockIdx.x * 128, blockIdx.y * BN, Ahi, Alo, Bt,
                             bias, Cf, Cb, M, K, N, As);
}

__global__ __launch_bounds__(256) void k_agg_fb(
    const u16* __restrict__ tmph, const int* __restrict__ rowptr,
    const int2* __restrict__ csr, const float* __restrict__ dinv,
    const float* __restrict__ bias, u16* __restrict__ hi,
    u16* __restrict__ lo, int n) {
  int iw = (int)((blockIdx.x * (size_t)blockDim.x + threadIdx.x) >> 6);
  int i = __builtin_amdgcn_readfirstlane(iw);
  if (i >= n) return;
  agg_node(i, tmph, rowptr, csr, dinv, bias, hi, lo, threadIdx.x & 63);
}

// ---------------- launch ----------------

extern "C" void kernel_launch(void* const* d_in, const int* in_sizes, int n_in,
                              void* d_out, int out_size, void* d_ws, size_t ws_size,
                              hipStream_t stream) {
  const float* x = (const float*)d_in[0];
  const int* eidx = (const int*)d_in[1];

  char* ws = (char*)d_ws;
  size_t off = 0;
  auto alloc = [&](size_t bytes) -> void* {
    void* p = ws + off;
    off += (bytes + 255) & ~(size_t)255;
    return p;
  };

  MegaArgs a;
  a.x = x;
  a.esrc = eidx;
  a.edst = eidx + N_EDGES;
  a.W_emb = (const float*)d_in[2];
  a.b_emb = (const float*)d_in[3];
  a.W_conv = (const float*)d_in[4];
  a.b_conv = (const float*)d_in[5];
  a.W_out = (const float*)d_in[6];
  a.b_out = (const float*)d_in[7];
  a.out = (float*)d_out;

  a.tmph = (u16*)alloc((size_t)N_NODES * DH * 2);
  a.h_hi = (u16*)alloc((size_t)N_NODES * DH * 2);
  a.h_lo = (u16*)alloc((size_t)N_NODES * DH * 2);
  a.x_f16 = a.h_lo;  // alias: x_f16 dead after emb GEMM; h_lo first written layer-3 agg
  a.dinv = (float*)alloc((size_t)N_NODES * 4);
  a.cnt = (int*)alloc((size_t)N_NODES * 4);
  a.rowptr = (int*)alloc((size_t)(N_NODES + 1) * 4);
  a.cursor = (int*)alloc((size_t)N_NODES * 4);
  a.bsum = (int*)alloc((size_t)((N_NODES + 255) / 256) * 4);
  a.csr = (int2*)alloc((size_t)N_EDGES * 8);
  a.Bt_emb = (u16*)alloc((size_t)W_EMB_SZ * 2);
  a.Bt_conv = (u16*)alloc((size_t)4 * W_CONV_SZ * 2);
  a.Bt_out = (u16*)alloc((size_t)W_OUT_SZ * 2);
  a.bEmbP = (float*)alloc((size_t)DH * 4);
  a.bConvP = (float*)alloc((size_t)4 * DH * 4);

  void* kargs[] = {&a};
  hipError_t err = hipLaunchCooperativeKernel((const void*)k_mega, dim3(MEGA_BLOCKS),
                                              dim3(256), kargs, 0, stream);
  if (err != hipSuccess) {
    // fallback: proven multi-dispatch path (round-11 structure)
    int nb = (N_NODES + 255) / 256;
    int eb = (N_EDGES + 255) / 256;
    int mb = (N_NODES + 127) / 128;
    int aggblocks = (N_NODES * 64 + 255) / 256;
    k_convert_fb<<<(CVT_TOT + 255) / 256, 256, 0, stream>>>(a);
    k_hist<<<eb, 256, 0, stream>>>(a.edst, a.cnt);
    k_scan1<<<nb, 256, 0, stream>>>(a.cnt, a.rowptr, a.bsum, a.dinv, N_NODES);
    k_scan2<<<1, 256, 0, stream>>>(a.bsum, nb);
    k_scan3<<<nb, 256, 0, stream>>>(a.rowptr, a.bsum, a.cursor, N_NODES);
    k_fill<<<eb, 256, 0, stream>>>(a.esrc, a.edst, a.dinv, a.cursor, a.csr, N_EDGES);
    {
      dim3 g(mb, 2);
      k_gemm<128, 1, 1><<<g, 256, 0, stream>>>(a.x_f16, nullptr, a.Bt_emb, a.bEmbP,
                                               nullptr, a.h_hi, N_NODES, DIN, DH);
    }
    for (int l = 0; l < NLAYERS; l++) {
      dim3 g(mb, 2);
      k_gemm<128, 1, 1><<<g, 256, 0, stream>>>(a.h_hi, nullptr,
                                               a.Bt_conv + (size_t)l * W_CONV_SZ,
                                               nullptr, nullptr, a.tmph, N_NODES, DH, DH);
      k_agg_fb<<<aggblocks, 256, 0, stream>>>(a.tmph, a.rowptr, a.csr, a.dinv,
                                              a.bConvP + (size_t)l * DH,
                                              a.h_hi, (l == 3) ? a.h_lo : nullptr,
                                              N_NODES);
    }
    {
      dim3 g(mb, 1);
      k_gemm<64, 3, 0><<<g, 256, 0, stream>>>(a.h_hi, a.h_lo, a.Bt_out, a.b_out,
                                              a.out, nullptr, N_NODES, DH, DOUT);
    }
  }
}

// Round 14
// 544.059 us; speedup vs baseline: 8.5029x; 8.5029x over previous
//
#include <hip/hip_runtime.h>
#include <math.h>

#define N_NODES 50000
#define N_EDGES 800000
#define DIN 128
#define DH 256
#define DOUT 64
#define NLAYERS 4

typedef unsigned short u16;
typedef __attribute__((ext_vector_type(8))) _Float16 half8;
typedef __attribute__((ext_vector_type(4))) float f32x4;
typedef __attribute__((ext_vector_type(4), aligned(8))) int int4a;

__device__ inline u16 f2h(float f) {
  _Float16 h = (_Float16)f;
  return *(u16*)&h;
}
__device__ inline float h2f(u16 u) {
  _Float16 h = *(_Float16*)&u;
  return (float)h;
}
// stored index j -> true feature index (perm: true c -> (c%16)*4 + c/16 per 64-seg)
__device__ inline int invp(int j) {
  int s = j >> 6, t = j & 63;
  return s * 64 + (t & 3) * 16 + (t >> 2);
}

#define GLD16(gp, lp)                                                        \
  __builtin_amdgcn_global_load_lds(                                          \
      (const __attribute__((address_space(1))) void*)(const void*)(gp),      \
      (__attribute__((address_space(3))) void*)(void*)(lp), 16, 0, 0)

// ---------------- preprocessing ----------------

// scan1 + dinv fused
__global__ void k_scan1(const int* __restrict__ cnt, int* __restrict__ rowptr,
                        int* __restrict__ bsum, float* __restrict__ dinv, int n) {
  __shared__ int sm[256];
  int i = blockIdx.x * 256 + threadIdx.x;
  int v = (i < n) ? cnt[i] : 0;
  if (i < n) dinv[i] = rsqrtf((float)v + 1.0f);  // +1 = self-loop
  sm[threadIdx.x] = v;
  __syncthreads();
  for (int off = 1; off < 256; off <<= 1) {
    int t = (threadIdx.x >= off) ? sm[threadIdx.x - off] : 0;
    __syncthreads();
    sm[threadIdx.x] += t;
    __syncthreads();
  }
  if (i < n) rowptr[i + 1] = sm[threadIdx.x];
  if (threadIdx.x == 255) bsum[blockIdx.x] = sm[255];
}

__global__ void k_scan2(int* bsum, int nb) {
  __shared__ int sm[256];
  int v = (threadIdx.x < nb) ? bsum[threadIdx.x] : 0;
  sm[threadIdx.x] = v;
  __syncthreads();
  for (int off = 1; off < 256; off <<= 1) {
    int t = (threadIdx.x >= off) ? sm[threadIdx.x - off] : 0;
    __syncthreads();
    sm[threadIdx.x] += t;
    __syncthreads();
  }
  if (threadIdx.x < nb) bsum[threadIdx.x] = sm[threadIdx.x] - v;
}

// scan3 + cursor init fused
__global__ void k_scan3(int* __restrict__ rowptr, const int* __restrict__ bsum,
                        int* __restrict__ cursor, int n) {
  int i = blockIdx.x * 256 + threadIdx.x;
  if (i < n) {
    int v = rowptr[i + 1] + bsum[blockIdx.x];
    rowptr[i + 1] = v;
    if (i + 1 < n) cursor[i + 1] = v;
  }
  if (blockIdx.x == 0 && threadIdx.x == 0) {
    rowptr[0] = 0;
    cursor[0] = 0;
  }
}

__global__ void k_fill(const int* __restrict__ src, const int* __restrict__ dst,
                       const float* __restrict__ dinv,
                       int* __restrict__ cursor, int2* __restrict__ csr, int e) {
  int i = blockIdx.x * blockDim.x + threadIdx.x;
  if (i < e) {
    int d = dst[i], s = src[i];
    int pos = atomicAdd(&cursor[d], 1);
    csr[pos] = make_int2(s, __float_as_int(dinv[s] * dinv[d]));
  }
}

// ---------------- convert: x, weights (k-inverse-perm), biases (perm), + count ----
#define X_Q (N_NODES * DIN / 4)        // 1,600,000 float4 groups
#define W_EMB_SZ (DIN * DH)            // 32768 (plain: emb k-dim is unpermuted x)
#define W_CONV_SZ (DH * DH)            // 65536
#define W_OUT_SZ (3 * DH * DOUT)       // 49152
#define W_TOT (W_EMB_SZ + 4 * W_CONV_SZ + W_OUT_SZ)
#define B_TOT (DH + 4 * DH)            // permuted b_emb + b_conv

__global__ void k_convert(const float* __restrict__ x, u16* __restrict__ x_f16,
                          const float* __restrict__ W_emb, const float* __restrict__ W_conv,
                          const float* __restrict__ W_out,
                          const float* __restrict__ b_emb, const float* __restrict__ b_conv,
                          u16* __restrict__ Bt_emb, u16* __restrict__ Bt_conv,
                          u16* __restrict__ Bt_out,
                          float* __restrict__ bEmbP, float* __restrict__ bConvP,
                          const int* __restrict__ edst, int* __restrict__ cnt) {
  int i = blockIdx.x * 256 + threadIdx.x;
  if (i < X_Q) {
    float4 v = ((const float4*)x)[i];
    ushort4 o;
    o.x = f2h(v.x); o.y = f2h(v.y); o.z = f2h(v.z); o.w = f2h(v.w);
    ((ushort4*)x_f16)[i] = o;
    return;
  }
  int t = i - X_Q;
  if (t < W_EMB_SZ) {
    int n = t >> 7, k = t & (DIN - 1);           // Bt_emb[n][k], k plain
    Bt_emb[t] = f2h(W_emb[k * DH + n]);
  } else if (t < W_EMB_SZ + 4 * W_CONV_SZ) {
    int j = t - W_EMB_SZ;
    int l = j >> 16, jj = j & (W_CONV_SZ - 1);
    int n = jj >> 8, k2 = jj & (DH - 1);         // Bt_conv[n][k2], k2 = perm space
    Bt_conv[j] = f2h(W_conv[l * W_CONV_SZ + invp(k2) * DH + n]);
  } else if (t < W_TOT) {
    int j = t - W_EMB_SZ - 4 * W_CONV_SZ;
    int n = j / (3 * DH), kp = j % (3 * DH);     // Bt_out[n][kp]: 0..255 hi,256.. lo,512.. hi
    int s0 = kp >> 8, k2 = kp & (DH - 1);
    float wv = W_out[invp(k2) * DOUT + n];
    u16 hiv = f2h(wv);
    u16 v = hiv;
    if (s0 == 1) v = f2h(wv - h2f(hiv));
    Bt_out[j] = v;
  } else {
    int t2 = t - W_TOT;
    if (t2 < B_TOT) {
      if (t2 < DH) bEmbP[t2] = b_emb[invp(t2)];
      else {
        int j = t2 - DH, l = j >> 8, jj = j & (DH - 1);
        bConvP[j] = b_conv[l * DH + invp(jj)];
      }
    } else {
      int t3 = t2 - B_TOT;
      if (t3 < N_EDGES) atomicAdd(&cnt[edst[t3]], 1);
    }
  }
}

// ---------------- f16 MFMA GEMM: A via LDS, B direct from L2 ----------------
// C[M][N] = A[M][K']·B2[K'][N]; A = (Ahi, Alo) f16 [M][K].
// NSPLIT=1: K'=K. NSPLIT=3: K'=3K, (Ahi·Bhi)+(Ahi·Blo)+(Alo·Bhi).
// Bt = B2^T [N][K'] f16 (L2-resident weight).
// BM=128, BK=64. NTHREADS=256: 4 waves (2M x 2N), wave tile 64 x BN/2.
// NTHREADS=512 (BN=256): 8 waves (2M x 4N), wave tile 64x64 -- ONE A-stage
// per block-row serves all 256 cols (kills the grid-y=2 A-restage of the
// BN=128 config; staging issues per wave halve; per-wave VGPR unchanged).
// A staged via GLD16 in fragment-order LDS (conflict-free); B frags from L2.
// EPI 0: Cf fp32 + bias, TRUE col order (scalar stores).
// EPI 1: Cb f16 + biasp, PERM col order (ushort4 stores); requires wave NT==4.
template <int BN, int NSPLIT, int EPI, int NTHREADS>
__global__ __launch_bounds__(NTHREADS) void k_gemm_mfma(
    const u16* __restrict__ Ahi, const u16* __restrict__ Alo,
    const u16* __restrict__ Bt, const float* __restrict__ bias,
    float* __restrict__ Cf, u16* __restrict__ Cb, int M, int K, int N) {
  constexpr int BM = 128, BK = 64;
  constexpr int WAVES = NTHREADS / 64;
  constexpr int WN = (BN == 256) ? 64 : BN / 2;
  constexpr int NT = WN / 16;
  __shared__ u16 As[2 * 8 * 512];  // (kb, g<8, lane*8) : 16 KB
  const int tid = threadIdx.x;
  const int w = tid >> 6, lane = tid & 63;
  const int q = lane >> 4, r = lane & 15;
  const int wmg = (WAVES == 8) ? (w >> 2) * 4 : (w >> 1) * 4;  // A group base
  const int wn = (WAVES == 8) ? (w & 3) * WN : (w & 1) * WN;
  const int m0 = blockIdx.x * BM, n0 = blockIdx.y * BN;
  const int Kp = NSPLIT * K;
  const int srow = lane & 15;         // staging source row within group
  const int sk = (lane >> 4) * 8;     // staging source k offset

  f32x4 acc[4][NT];
#pragma unroll
  for (int t = 0; t < 4; t++)
#pragma unroll
    for (int u = 0; u < NT; u++) acc[t][u] = (f32x4){0.f, 0.f, 0.f, 0.f};

  for (int k0 = 0; k0 < Kp; k0 += BK) {
    const u16* Aptr;
    int ka;
    if (NSPLIT == 1) {
      Aptr = Ahi; ka = k0;
    } else {
      Aptr = (k0 < 2 * K) ? Ahi : Alo;
      ka = (k0 < K) ? k0 : ((k0 < 2 * K) ? (k0 - K) : (k0 - 2 * K));
    }
    // stage A: 16 slots over WAVES waves
    if constexpr (WAVES == 8) {
#pragma unroll
      for (int ii = 0; ii < 2; ii++) {
        int g = w, kb = ii;
        int grow = m0 + g * 16 + srow;
        if (grow > M - 1) grow = M - 1;
        const u16* gp = Aptr + (size_t)grow * K + ka + kb * 32 + sk;
        GLD16(gp, &As[(kb * 8 + g) * 512] + (size_t)lane * 8);
      }
    } else {
#pragma unroll
      for (int ii = 0; ii < 4; ii++) {
        int g = w * 2 + (ii & 1), kb = ii >> 1;
        int grow = m0 + g * 16 + srow;
        if (grow > M - 1) grow = M - 1;
        const u16* gp = Aptr + (size_t)grow * K + ka + kb * 32 + sk;
        GLD16(gp, &As[(kb * 8 + g) * 512] + (size_t)lane * 8);
      }
    }
    __syncthreads();
#pragma unroll
    for (int kb = 0; kb < 2; kb++) {
      half8 af[4], bfr[NT];
#pragma unroll
      for (int u = 0; u < NT; u++)
        bfr[u] = *(const half8*)(Bt + (size_t)(n0 + wn + u * 16 + r) * Kp +
                                 k0 + kb * 32 + q * 8);
#pragma unroll
      for (int t = 0; t < 4; t++)
        af[t] = *(const half8*)&As[((kb * 8 + wmg + t) * 64 + lane) * 8];
#pragma unroll
      for (int t = 0; t < 4; t++)
#pragma unroll
        for (int u = 0; u < NT; u++)
          acc[t][u] = __builtin_amdgcn_mfma_f32_16x16x32_f16(af[t], bfr[u], acc[t][u], 0, 0, 0);
    }
    __syncthreads();
  }

  const int rowb = m0 + ((WAVES == 8) ? (w >> 2) : (w >> 1)) * 64;
  if constexpr (EPI == 1) {
    static_assert(NT == 4, "perm epilogue requires wave NT==4");
    // perm epilogue: lane holds true cols cb+u*16+r -> stored cb + r*4 + u
    int cb = n0 + wn;
    int c = cb + r * 4;
    float4 bp = bias ? *(const float4*)(bias + c)
                     : make_float4(0.f, 0.f, 0.f, 0.f);
#pragma unroll
    for (int t = 0; t < 4; t++) {
#pragma unroll
      for (int rg = 0; rg < 4; rg++) {
        int row = rowb + t * 16 + q * 4 + rg;
        if (row < M) {
          ushort4 o;
          o.x = f2h(acc[t][0][rg] + bp.x);
          o.y = f2h(acc[t][1][rg] + bp.y);
          o.z = f2h(acc[t][2][rg] + bp.z);
          o.w = f2h(acc[t][3][rg] + bp.w);
          *(ushort4*)(Cb + (size_t)row * N + c) = o;
        }
      }
    }
  } else {
    float bv[NT];
#pragma unroll
    for (int u = 0; u < NT; u++) bv[u] = bias ? bias[n0 + wn + u * 16 + r] : 0.f;
#pragma unroll
    for (int t = 0; t < 4; t++) {
#pragma unroll
      for (int rg = 0; rg < 4; rg++) {
        int row = rowb + t * 16 + q * 4 + rg;
        if (row < M) {
#pragma unroll
          for (int u = 0; u < NT; u++) {
            int col = n0 + wn + u * 16 + r;
            Cf[(size_t)row * N + col] = acc[t][u][rg] + bv[u];
          }
        }
      }
    }
  }
}

// ---------------- aggregation (round-1 form, proven 60.5 us) ----------------
// h[i] = tanh(b + dinv[i]^2*tmp[i] + sum_e w_e*tmp[src_e]); writes f16 hi (+lo).
// Wave-per-node; i wave-uniform (readfirstlane) -> rowptr/dinv/csr on the
// scalar pipe; flat 16-edge chunks (one csr->gather dependency round);
// clamped-16 tail keeps summation order bitwise identical.
__global__ __launch_bounds__(256) void k_aggregate(
    const u16* __restrict__ tmph,
    const int* __restrict__ rowptr, const int2* __restrict__ csr,
    const float* __restrict__ dinv, const float* __restrict__ bias,
    u16* __restrict__ hi, u16* __restrict__ lo, int n) {
  int iw = (int)((blockIdx.x * (size_t)blockDim.x + threadIdx.x) >> 6);
  int i = __builtin_amdgcn_readfirstlane(iw);
  if (i >= n) return;
  int lane = threadIdx.x & 63;
  float w0 = dinv[i];
  w0 *= w0;
  const ushort4* T = (const ushort4*)tmph;
  float4 bv = ((const float4*)bias)[lane];
  int s = rowptr[i], e = rowptr[i + 1];
  ushort4 t0 = T[(size_t)i * 64 + lane];
  float ax = bv.x + w0 * h2f(t0.x);
  float ay = bv.y + w0 * h2f(t0.y);
  float az = bv.z + w0 * h2f(t0.z);
  float aw = bv.w + w0 * h2f(t0.w);
  int j = s;
  // main: full 16-edge chunks, csr pairs via wide uniform loads
  for (; j + 16 <= e; j += 16) {
    int4a q[8];
#pragma unroll
    for (int u = 0; u < 8; u++) q[u] = *(const int4a*)(csr + j + 2 * u);
    ushort4 v[16];
#pragma unroll
    for (int u = 0; u < 8; u++) {
      v[2 * u] = T[(size_t)q[u].x * 64 + lane];
      v[2 * u + 1] = T[(size_t)q[u].z * 64 + lane];
    }
#pragma unroll
    for (int u = 0; u < 8; u++) {
      float f0 = __int_as_float(q[u].y);
      ax += f0 * h2f(v[2 * u].x);
      ay += f0 * h2f(v[2 * u].y);
      az += f0 * h2f(v[2 * u].z);
      aw += f0 * h2f(v[2 * u].w);
      float f1 = __int_as_float(q[u].w);
      ax += f1 * h2f(v[2 * u + 1].x);
      ay += f1 * h2f(v[2 * u + 1].y);
      az += f1 * h2f(v[2 * u + 1].z);
      aw += f1 * h2f(v[2 * u + 1].w);
    }
  }
  // tail: one clamped 16-chunk (<=15 real edges); padded slots add 0.0
  if (j < e) {
    int2 c[16];
    float f[16];
    ushort4 v[16];
#pragma unroll
    for (int u = 0; u < 16; u++) {
      int idx = j + u;
      int cl = idx < e ? idx : e - 1;
      c[u] = csr[cl];
      f[u] = idx < e ? __int_as_float(c[u].y) : 0.f;
    }
#pragma unroll
    for (int u = 0; u < 16; u++) v[u] = T[(size_t)c[u].x * 64 + lane];
#pragma unroll
    for (int u = 0; u < 16; u++) {
      ax += f[u] * h2f(v[u].x);
      ay += f[u] * h2f(v[u].y);
      az += f[u] * h2f(v[u].z);
      aw += f[u] * h2f(v[u].w);
    }
  }
  float ox = tanhf(ax), oy = tanhf(ay), oz = tanhf(az), ow = tanhf(aw);
  size_t base = (size_t)i * DH + lane * 4;
  ushort4 hv;
  hv.x = f2h(ox); hv.y = f2h(oy); hv.z = f2h(oz); hv.w = f2h(ow);
  *(ushort4*)(hi + base) = hv;
  if (lo) {
    ushort4 lv;
    lv.x = f2h(ox - h2f(hv.x));
    lv.y = f2h(oy - h2f(hv.y));
    lv.z = f2h(oz - h2f(hv.z));
    lv.w = f2h(ow - h2f(hv.w));
    *(ushort4*)(lo + base) = lv;
  }
}

// ---------------- launch ----------------

extern "C" void kernel_launch(void* const* d_in, const int* in_sizes, int n_in,
                              void* d_out, int out_size, void* d_ws, size_t ws_size,
                              hipStream_t stream) {
  const float* x = (const float*)d_in[0];
  const int* eidx = (const int*)d_in[1];
  const int* esrc = eidx;
  const int* edst = eidx + N_EDGES;
  const float* W_emb = (const float*)d_in[2];
  const float* b_emb = (const float*)d_in[3];
  const float* W_conv = (const float*)d_in[4];
  const float* b_conv = (const float*)d_in[5];
  const float* W_out = (const float*)d_in[6];
  const float* b_out = (const float*)d_in[7];
  float* out = (float*)d_out;

  char* ws = (char*)d_ws;
  size_t off = 0;
  auto alloc = [&](size_t bytes) -> void* {
    void* p = ws + off;
    off += (bytes + 255) & ~(size_t)255;
    return p;
  };
  u16* tmph = (u16*)alloc((size_t)N_NODES * DH * 2);
  u16* h_hi = (u16*)alloc((size_t)N_NODES * DH * 2);
  u16* h_lo = (u16*)alloc((size_t)N_NODES * DH * 2);
  u16* x_f16 = h_lo;  // alias: x_f16 dead after emb GEMM; h_lo first written at layer-3 agg
  float* dinv = (float*)alloc((size_t)N_NODES * 4);
  int* cnt = (int*)alloc((size_t)N_NODES * 4);
  int* rowptr = (int*)alloc((size_t)(N_NODES + 1) * 4);
  int* cursor = (int*)alloc((size_t)N_NODES * 4);
  int* bsum = (int*)alloc((size_t)((N_NODES + 255) / 256) * 4);
  int2* csr = (int2*)alloc((size_t)N_EDGES * 8);
  u16* Bt_emb = (u16*)alloc((size_t)W_EMB_SZ * 2);
  u16* Bt_conv = (u16*)alloc((size_t)4 * W_CONV_SZ * 2);
  u16* Bt_out = (u16*)alloc((size_t)W_OUT_SZ * 2);
  float* bEmbP = (float*)alloc((size_t)DH * 4);
  float* bConvP = (float*)alloc((size_t)4 * DH * 4);

  int nb = (N_NODES + 255) / 256;
  int eb = (N_EDGES + 255) / 256;

  (void)hipMemsetAsync(cnt, 0, (size_t)N_NODES * 4, stream);
  {
    int tot = X_Q + W_TOT + B_TOT + N_EDGES;
    k_convert<<<(tot + 255) / 256, 256, 0, stream>>>(x, x_f16, W_emb, W_conv, W_out,
                                                     b_emb, b_conv, Bt_emb, Bt_conv,
                                                     Bt_out, bEmbP, bConvP, edst, cnt);
  }
  k_scan1<<<nb, 256, 0, stream>>>(cnt, rowptr, bsum, dinv, N_NODES);
  k_scan2<<<1, 256, 0, stream>>>(bsum, nb);
  k_scan3<<<nb, 256, 0, stream>>>(rowptr, bsum, cursor, N_NODES);
  k_fill<<<eb, 256, 0, stream>>>(esrc, edst, dinv, cursor, csr, N_EDGES);

  int mblocks = (N_NODES + 127) / 128;  // 391
  int aggblocks = (N_NODES * 64 + 255) / 256;

  // emb: h0 = x @ W_emb + b_emb -> f16 h_hi (perm cols); BN=256, one A-stage
  k_gemm_mfma<256, 1, 1, 512><<<mblocks, 512, 0, stream>>>(
      x_f16, nullptr, Bt_emb, bEmbP, nullptr, h_hi, N_NODES, DIN, DH);
  // conv layers: BN=256 single-A-stage GEMM -> tmph (row-major, perm cols);
  // layer 3 agg also emits h_lo for the final split GEMM
  for (int l = 0; l < NLAYERS; l++) {
    k_gemm_mfma<256, 1, 1, 512><<<mblocks, 512, 0, stream>>>(
        h_hi, nullptr, Bt_conv + (size_t)l * W_CONV_SZ, nullptr,
        nullptr, tmph, N_NODES, DH, DH);
    k_aggregate<<<aggblocks, 256, 0, stream>>>(tmph, rowptr, csr, dinv,
                                               bConvP + (size_t)l * DH,
                                               h_hi, (l == 3) ? h_lo : nullptr, N_NODES);
  }
  // out = h4 @ W_out + b_out (split-3, fp32 out, TRUE col order)
  {
    dim3 g(mblocks, 1);
    k_gemm_mfma<64, 3, 0, 256><<<g, 256, 0, stream>>>(h_hi, h_lo, Bt_out, b_out,
                                                      out, nullptr, N_NODES, DH, DOUT);
  }
}